// Round 10
// baseline (200.550 us; speedup 1.0000x reference)
//
#include <hip/hip_runtime.h>

#define NMAPS 8
#define BATCH 32
#define DLEN  150528              // 3*224*224
#define D4    (DLEN / 4)          // 37632 float4 per (map, batch) row
#define NPAIR 36                  // i<=j pairs incl diagonal (diag = norm^2)
#define CHUNKS 32                 // blocks per batch element
#define TPB   256
#define JSTRIDE (CHUNKS * TPB)    // 8192 float4
#define REPEAT 4                  // measurement: 4 identical passes
#define NITEMS (BATCH * NPAIR)

// ---- MEASUREMENT ROUND ----
// gram does REPEAT identical passes (cosine is exactly invariant to the
// uniform scaling of dots & norms^2, so the result is unchanged) so the
// dispatch exceeds the 86us harness fills and appears in rocprof top-5.

__global__ __launch_bounds__(TPB) void gram_kernel(const float* __restrict__ xf,
                                                   float* __restrict__ partial) {
    const int b     = blockIdx.x;   // 0..31
    const int chunk = blockIdx.y;   // 0..31
    const int tid   = threadIdx.x;

    const float4* xb = reinterpret_cast<const float4*>(xf) + (size_t)b * D4;
    const size_t strideI = (size_t)BATCH * D4;   // float4 stride between maps

    float acc[NPAIR];
#pragma unroll
    for (int k = 0; k < NPAIR; ++k) acc[k] = 0.0f;

#pragma unroll 1
    for (int r = 0; r < REPEAT; ++r) {
#pragma unroll 1
        for (int j = chunk * TPB + tid; j < D4; j += JSTRIDE) {
            float4 v[NMAPS];
#pragma unroll
            for (int i = 0; i < NMAPS; ++i)
                v[i] = xb[(size_t)i * strideI + j];
            int k = 0;
#pragma unroll
            for (int i = 0; i < NMAPS; ++i) {
#pragma unroll
                for (int jj = i; jj < NMAPS; ++jj) {
                    acc[k] += v[i].x * v[jj].x + v[i].y * v[jj].y +
                              v[i].z * v[jj].z + v[i].w * v[jj].w;
                    ++k;
                }
            }
        }
    }

    const int lane = tid & 63;
    const int wave = tid >> 6;
    __shared__ float red[TPB / 64][NPAIR];
#pragma unroll
    for (int k = 0; k < NPAIR; ++k) {
        float s = acc[k];
#pragma unroll
        for (int off = 32; off > 0; off >>= 1) s += __shfl_down(s, off, 64);
        if (lane == 0) red[wave][k] = s;
    }
    __syncthreads();
    if (tid < NPAIR) {
        partial[((size_t)b * NPAIR + tid) * CHUNKS + chunk] =
            red[0][tid] + red[1][tid] + red[2][tid] + red[3][tid];
    }
}

__global__ __launch_bounds__(256) void finalize_kernel(const float* __restrict__ partial,
                                                       float* __restrict__ out) {
    const int tid = threadIdx.x;
    __shared__ float dots_s[NITEMS];
    __shared__ float norms[BATCH][NMAPS];

    for (int item = tid; item < NITEMS; item += 256) {
        const float4* p = reinterpret_cast<const float4*>(partial + (size_t)item * CHUNKS);
        float s = 0.0f;
#pragma unroll
        for (int c = 0; c < CHUNKS / 4; ++c) {
            float4 t = p[c];
            s += t.x + t.y + t.z + t.w;
        }
        dots_s[item] = s;
    }
    __syncthreads();
    {
        int bb = tid >> 3, i = tid & 7;
        int diag = 8 * i - (i * (i - 1)) / 2;
        norms[bb][i] = sqrtf(dots_s[bb * NPAIR + diag]);
    }
    __syncthreads();

    float sum = 0.0f;
    for (int item = tid; item < 28 * BATCH; item += 256) {
        int p = item >> 5;
        int bb = item & 31;
        int i = 0, rem = p;
        while (rem >= 7 - i) { rem -= 7 - i; ++i; }
        int j = i + 1 + rem;
        int k = 8 * i - (i * (i - 1)) / 2 + (j - i);
        float d   = fabsf(dots_s[bb * NPAIR + k]);
        float den = fmaxf(norms[bb][i] * norms[bb][j], 1e-8f);
        sum += d / den;
    }

    const int lane = tid & 63, wave = tid >> 6;
    __shared__ float red2[4];
#pragma unroll
    for (int off = 32; off > 0; off >>= 1) sum += __shfl_down(sum, off, 64);
    if (lane == 0) red2[wave] = sum;
    __syncthreads();
    if (tid == 0)
        out[0] = (red2[0] + red2[1] + red2[2] + red2[3]) / (28.0f * BATCH);
}

// Pure linear read probe: 4 passes over the whole 154 MB buffer, one
// contiguous grid-stride stream. Measures the chip's read-only ceiling.
#define PROBE_BLOCKS 2048
__global__ __launch_bounds__(256) void readprobe_kernel(const float* __restrict__ xf,
                                                        float* __restrict__ probe_out) {
    const float4* x4 = reinterpret_cast<const float4*>(xf);
    const size_t total = (size_t)NMAPS * BATCH * D4;   // 9,633,792 float4
    float s = 0.0f;
#pragma unroll 1
    for (int r = 0; r < REPEAT; ++r) {
#pragma unroll 1
        for (size_t j = (size_t)blockIdx.x * 256 + threadIdx.x; j < total;
             j += (size_t)PROBE_BLOCKS * 256) {
            float4 v = x4[j];
            s += v.x + v.y + v.z + v.w;
        }
    }
    const int lane = threadIdx.x & 63, wave = threadIdx.x >> 6;
    __shared__ float red[4];
#pragma unroll
    for (int off = 32; off > 0; off >>= 1) s += __shfl_down(s, off, 64);
    if (lane == 0) red[wave] = s;
    __syncthreads();
    if (threadIdx.x == 0)
        probe_out[blockIdx.x] = red[0] + red[1] + red[2] + red[3];
}

extern "C" void kernel_launch(void* const* d_in, const int* in_sizes, int n_in,
                              void* d_out, int out_size, void* d_ws, size_t ws_size,
                              hipStream_t stream) {
    const float* x       = (const float*)d_in[0];
    float*       out     = (float*)d_out;
    float*       partial = (float*)d_ws;   // 147456 B

    dim3 grid(BATCH, CHUNKS);
    gram_kernel<<<grid, TPB, 0, stream>>>(x, partial);
    finalize_kernel<<<1, 256, 0, stream>>>(partial, out);

    // independent read-ceiling probe (does not affect d_out)
    if (ws_size >= 160 * 1024 + PROBE_BLOCKS * sizeof(float)) {
        float* probe_out = (float*)((char*)d_ws + 160 * 1024);
        readprobe_kernel<<<PROBE_BLOCKS, 256, 0, stream>>>(x, probe_out);
    }
}

// Round 11
// 47.732 us; speedup vs baseline: 4.2016x; 4.2016x over previous
//
#include <hip/hip_runtime.h>

#define NMAPS 8
#define BATCH 32
#define DLEN  150528              // 3*224*224
#define D4    (DLEN / 4)          // 37632 float4 per (map, batch) row
#define NPAIR 36                  // i<=j pairs incl diagonal (diag = norm^2)
#define CHUNKS 32                 // blocks per batch element
#define TPB   512                 // 8 waves/block; 1024 blocks -> 32 waves/CU
#define JSTRIDE (CHUNKS * TPB)    // 16384 float4
#define NITEMS (BATCH * NPAIR)

typedef float floatx4 __attribute__((ext_vector_type(4)));

// Kernel 1: 36 unique pairwise dots per batch element, single pass.
// Max-occupancy variant: 32 waves/CU to cover load latency (R10 showed
// 40% occupancy, HBM 29%, VALU 19% -- latency-bound, nothing saturated).
__global__ __launch_bounds__(TPB) void gram_kernel(const float* __restrict__ xf,
                                                   float* __restrict__ partial) {
    const int b     = blockIdx.x;   // 0..31
    const int chunk = blockIdx.y;   // 0..31
    const int tid   = threadIdx.x;

    const floatx4* xb = reinterpret_cast<const floatx4*>(xf) + (size_t)b * D4;
    const size_t strideI = (size_t)BATCH * D4;   // float4 stride between maps

    float acc[NPAIR];
#pragma unroll
    for (int k = 0; k < NPAIR; ++k) acc[k] = 0.0f;

#pragma unroll 1
    for (int j = chunk * TPB + tid; j < D4; j += JSTRIDE) {
        floatx4 v[NMAPS];
#pragma unroll
        for (int i = 0; i < NMAPS; ++i)
            v[i] = __builtin_nontemporal_load(&xb[(size_t)i * strideI + j]);
        int k = 0;
#pragma unroll
        for (int i = 0; i < NMAPS; ++i) {
#pragma unroll
            for (int jj = i; jj < NMAPS; ++jj) {
                acc[k] += v[i].x * v[jj].x + v[i].y * v[jj].y +
                          v[i].z * v[jj].z + v[i].w * v[jj].w;
                ++k;
            }
        }
    }

    // wave shuffle reduce, then cross-wave LDS reduce (8 waves)
    const int lane = tid & 63;
    const int wave = tid >> 6;
    __shared__ float red[TPB / 64][NPAIR];
#pragma unroll
    for (int k = 0; k < NPAIR; ++k) {
        float s = acc[k];
#pragma unroll
        for (int off = 32; off > 0; off >>= 1) s += __shfl_down(s, off, 64);
        if (lane == 0) red[wave][k] = s;
    }
    __syncthreads();
    if (tid < NPAIR) {
        float t = 0.0f;
#pragma unroll
        for (int w = 0; w < TPB / 64; ++w) t += red[w][tid];
        // layout: partial[(b*36+k)*CHUNKS + chunk] -> finalize reads float4
        partial[((size_t)b * NPAIR + tid) * CHUNKS + chunk] = t;
    }
}

// Kernel 2: sum partials over chunks, then cosine epilogue. One block.
__global__ __launch_bounds__(256) void finalize_kernel(const float* __restrict__ partial,
                                                       float* __restrict__ out) {
    const int tid = threadIdx.x;
    __shared__ float dots_s[NITEMS];          // [b][k]
    __shared__ float norms[BATCH][NMAPS];

    for (int item = tid; item < NITEMS; item += 256) {
        const float4* p = reinterpret_cast<const float4*>(partial + (size_t)item * CHUNKS);
        float s = 0.0f;
#pragma unroll
        for (int c = 0; c < CHUNKS / 4; ++c) {
            float4 t = p[c];
            s += t.x + t.y + t.z + t.w;
        }
        dots_s[item] = s;
    }
    __syncthreads();
    {
        int bb = tid >> 3, i = tid & 7;             // 256 = 32*8
        int diag = 8 * i - (i * (i - 1)) / 2;
        norms[bb][i] = sqrtf(dots_s[bb * NPAIR + diag]);
    }
    __syncthreads();

    float sum = 0.0f;
    for (int item = tid; item < 28 * BATCH; item += 256) {
        int p = item >> 5;   // pair 0..27
        int bb = item & 31;
        int i = 0, rem = p;
        while (rem >= 7 - i) { rem -= 7 - i; ++i; }
        int j = i + 1 + rem;
        int k = 8 * i - (i * (i - 1)) / 2 + (j - i);
        float d   = fabsf(dots_s[bb * NPAIR + k]);
        float den = fmaxf(norms[bb][i] * norms[bb][j], 1e-8f);
        sum += d / den;
    }

    const int lane = tid & 63, wave = tid >> 6;
    __shared__ float red2[4];
#pragma unroll
    for (int off = 32; off > 0; off >>= 1) sum += __shfl_down(sum, off, 64);
    if (lane == 0) red2[wave] = sum;
    __syncthreads();
    if (tid == 0)
        out[0] = (red2[0] + red2[1] + red2[2] + red2[3]) / (28.0f * BATCH);
}

extern "C" void kernel_launch(void* const* d_in, const int* in_sizes, int n_in,
                              void* d_out, int out_size, void* d_ws, size_t ws_size,
                              hipStream_t stream) {
    const float* x       = (const float*)d_in[0];
    float*       out     = (float*)d_out;
    float*       partial = (float*)d_ws;   // NITEMS*CHUNKS floats = 147456 B

    dim3 grid(BATCH, CHUNKS);
    gram_kernel<<<grid, TPB, 0, stream>>>(x, partial);
    finalize_kernel<<<1, 256, 0, stream>>>(partial, out);
}

// Round 12
// 47.684 us; speedup vs baseline: 4.2059x; 1.0010x over previous
//
#include <hip/hip_runtime.h>

#define NMAPS 8
#define BATCH 32
#define DLEN  150528              // 3*224*224
#define D4    (DLEN / 4)          // 37632 float4 per (map, batch) row
#define NPAIR 36                  // i<=j pairs incl diagonal (diag = norm^2)
#define CHUNKS 32                 // blocks per batch element
#define TPB   512                 // 8 waves/block; 1024 blocks -> 32 waves/CU
#define JSTRIDE (CHUNKS * TPB)    // 16384 float4
#define NITEMS (BATCH * NPAIR)

typedef float floatx4 __attribute__((ext_vector_type(4)));

// Kernel 1: 36 unique pairwise dots per batch element, single pass.
// Max-occupancy variant: 32 waves/CU to cover load latency (R10 showed
// 40% occupancy, HBM 29%, VALU 19% -- latency-bound, nothing saturated).
__global__ __launch_bounds__(TPB) void gram_kernel(const float* __restrict__ xf,
                                                   float* __restrict__ partial) {
    const int b     = blockIdx.x;   // 0..31
    const int chunk = blockIdx.y;   // 0..31
    const int tid   = threadIdx.x;

    const floatx4* xb = reinterpret_cast<const floatx4*>(xf) + (size_t)b * D4;
    const size_t strideI = (size_t)BATCH * D4;   // float4 stride between maps

    float acc[NPAIR];
#pragma unroll
    for (int k = 0; k < NPAIR; ++k) acc[k] = 0.0f;

#pragma unroll 1
    for (int j = chunk * TPB + tid; j < D4; j += JSTRIDE) {
        floatx4 v[NMAPS];
#pragma unroll
        for (int i = 0; i < NMAPS; ++i)
            v[i] = __builtin_nontemporal_load(&xb[(size_t)i * strideI + j]);
        int k = 0;
#pragma unroll
        for (int i = 0; i < NMAPS; ++i) {
#pragma unroll
            for (int jj = i; jj < NMAPS; ++jj) {
                acc[k] += v[i].x * v[jj].x + v[i].y * v[jj].y +
                          v[i].z * v[jj].z + v[i].w * v[jj].w;
                ++k;
            }
        }
    }

    // wave shuffle reduce, then cross-wave LDS reduce (8 waves)
    const int lane = tid & 63;
    const int wave = tid >> 6;
    __shared__ float red[TPB / 64][NPAIR];
#pragma unroll
    for (int k = 0; k < NPAIR; ++k) {
        float s = acc[k];
#pragma unroll
        for (int off = 32; off > 0; off >>= 1) s += __shfl_down(s, off, 64);
        if (lane == 0) red[wave][k] = s;
    }
    __syncthreads();
    if (tid < NPAIR) {
        float t = 0.0f;
#pragma unroll
        for (int w = 0; w < TPB / 64; ++w) t += red[w][tid];
        // layout: partial[(b*36+k)*CHUNKS + chunk] -> finalize reads float4
        partial[((size_t)b * NPAIR + tid) * CHUNKS + chunk] = t;
    }
}

// Kernel 2: sum partials over chunks, then cosine epilogue. One block.
__global__ __launch_bounds__(256) void finalize_kernel(const float* __restrict__ partial,
                                                       float* __restrict__ out) {
    const int tid = threadIdx.x;
    __shared__ float dots_s[NITEMS];          // [b][k]
    __shared__ float norms[BATCH][NMAPS];

    for (int item = tid; item < NITEMS; item += 256) {
        const float4* p = reinterpret_cast<const float4*>(partial + (size_t)item * CHUNKS);
        float s = 0.0f;
#pragma unroll
        for (int c = 0; c < CHUNKS / 4; ++c) {
            float4 t = p[c];
            s += t.x + t.y + t.z + t.w;
        }
        dots_s[item] = s;
    }
    __syncthreads();
    {
        int bb = tid >> 3, i = tid & 7;             // 256 = 32*8
        int diag = 8 * i - (i * (i - 1)) / 2;
        norms[bb][i] = sqrtf(dots_s[bb * NPAIR + diag]);
    }
    __syncthreads();

    float sum = 0.0f;
    for (int item = tid; item < 28 * BATCH; item += 256) {
        int p = item >> 5;   // pair 0..27
        int bb = item & 31;
        int i = 0, rem = p;
        while (rem >= 7 - i) { rem -= 7 - i; ++i; }
        int j = i + 1 + rem;
        int k = 8 * i - (i * (i - 1)) / 2 + (j - i);
        float d   = fabsf(dots_s[bb * NPAIR + k]);
        float den = fmaxf(norms[bb][i] * norms[bb][j], 1e-8f);
        sum += d / den;
    }

    const int lane = tid & 63, wave = tid >> 6;
    __shared__ float red2[4];
#pragma unroll
    for (int off = 32; off > 0; off >>= 1) sum += __shfl_down(sum, off, 64);
    if (lane == 0) red2[wave] = sum;
    __syncthreads();
    if (tid == 0)
        out[0] = (red2[0] + red2[1] + red2[2] + red2[3]) / (28.0f * BATCH);
}

extern "C" void kernel_launch(void* const* d_in, const int* in_sizes, int n_in,
                              void* d_out, int out_size, void* d_ws, size_t ws_size,
                              hipStream_t stream) {
    const float* x       = (const float*)d_in[0];
    float*       out     = (float*)d_out;
    float*       partial = (float*)d_ws;   // NITEMS*CHUNKS floats = 147456 B

    dim3 grid(BATCH, CHUNKS);
    gram_kernel<<<grid, TPB, 0, stream>>>(x, partial);
    finalize_kernel<<<1, 256, 0, stream>>>(partial, out);
}

// Round 13
// 43.659 us; speedup vs baseline: 4.5935x; 1.0922x over previous
//
#include <hip/hip_runtime.h>

#define NMAPS 8
#define BATCH 32
#define DLEN  150528              // 3*224*224
#define D4    (DLEN / 4)          // 37632 float4 per (map, batch) row
#define NPAIR 36                  // i<=j pairs incl diagonal (diag = norm^2)
#define CHUNKS 49                 // 37632 = 3 * 49 * 256  -> exactly 3 iters/thread
#define TPB   256
#define JSTRIDE (CHUNKS * TPB)    // 12544 float4
#define NITEMS (BATCH * NPAIR)    // 1152

typedef float floatx4 __attribute__((ext_vector_type(4)));

// Kernel 1: 36 unique pairwise dots per batch element, single pass.
// R7 body (nt float4 direct loads) + higher occupancy: 1568 blocks
// (~6.1/CU, ~25 waves/CU) and a perfectly uniform 3-iteration loop.
__global__ __launch_bounds__(TPB) void gram_kernel(const float* __restrict__ xf,
                                                   float* __restrict__ partial) {
    const int b     = blockIdx.x;   // 0..31
    const int chunk = blockIdx.y;   // 0..48
    const int tid   = threadIdx.x;

    const floatx4* xb = reinterpret_cast<const floatx4*>(xf) + (size_t)b * D4;
    const size_t strideI = (size_t)BATCH * D4;   // float4 stride between maps

    float acc[NPAIR];
#pragma unroll
    for (int k = 0; k < NPAIR; ++k) acc[k] = 0.0f;

    const int j0 = chunk * TPB + tid;
#pragma unroll 1
    for (int it = 0; it < 3; ++it) {              // exact, uniform trip count
        const size_t j = (size_t)j0 + (size_t)it * JSTRIDE;
        floatx4 v[NMAPS];
#pragma unroll
        for (int i = 0; i < NMAPS; ++i)
            v[i] = __builtin_nontemporal_load(&xb[(size_t)i * strideI + j]);
        int k = 0;
#pragma unroll
        for (int i = 0; i < NMAPS; ++i) {
#pragma unroll
            for (int jj = i; jj < NMAPS; ++jj) {
                acc[k] += v[i].x * v[jj].x + v[i].y * v[jj].y +
                          v[i].z * v[jj].z + v[i].w * v[jj].w;
                ++k;
            }
        }
    }

    // wave shuffle reduce, then cross-wave LDS reduce
    const int lane = tid & 63;
    const int wave = tid >> 6;
    __shared__ float red[TPB / 64][NPAIR];
#pragma unroll
    for (int k = 0; k < NPAIR; ++k) {
        float s = acc[k];
#pragma unroll
        for (int off = 32; off > 0; off >>= 1) s += __shfl_down(s, off, 64);
        if (lane == 0) red[wave][k] = s;
    }
    __syncthreads();
    if (tid < NPAIR) {
        // layout: partial[chunk][b*36 + k]
        partial[(size_t)chunk * NITEMS + b * NPAIR + tid] =
            red[0][tid] + red[1][tid] + red[2][tid] + red[3][tid];
    }
}

// Kernel 2: sum partials over the 49 chunks, then cosine epilogue. One block.
__global__ __launch_bounds__(256) void finalize_kernel(const float* __restrict__ partial,
                                                       float* __restrict__ out) {
    const int tid = threadIdx.x;
    __shared__ float dots_s[NITEMS];          // [b][k]
    __shared__ float norms[BATCH][NMAPS];

    for (int item = tid; item < NITEMS; item += 256) {
        float s = 0.0f;
#pragma unroll
        for (int c = 0; c < CHUNKS; ++c)
            s += partial[(size_t)c * NITEMS + item];   // coalesced per c-slice
        dots_s[item] = s;
    }
    __syncthreads();
    {
        int bb = tid >> 3, i = tid & 7;             // 256 = 32*8
        int diag = 8 * i - (i * (i - 1)) / 2;
        norms[bb][i] = sqrtf(dots_s[bb * NPAIR + diag]);
    }
    __syncthreads();

    float sum = 0.0f;
    for (int item = tid; item < 28 * BATCH; item += 256) {
        int p = item >> 5;   // pair 0..27
        int bb = item & 31;
        int i = 0, rem = p;
        while (rem >= 7 - i) { rem -= 7 - i; ++i; }
        int j = i + 1 + rem;
        int k = 8 * i - (i * (i - 1)) / 2 + (j - i);
        float d   = fabsf(dots_s[bb * NPAIR + k]);
        float den = fmaxf(norms[bb][i] * norms[bb][j], 1e-8f);
        sum += d / den;
    }

    const int lane = tid & 63, wave = tid >> 6;
    __shared__ float red2[4];
#pragma unroll
    for (int off = 32; off > 0; off >>= 1) sum += __shfl_down(sum, off, 64);
    if (lane == 0) red2[wave] = sum;
    __syncthreads();
    if (tid == 0)
        out[0] = (red2[0] + red2[1] + red2[2] + red2[3]) / (28.0f * BATCH);
}

extern "C" void kernel_launch(void* const* d_in, const int* in_sizes, int n_in,
                              void* d_out, int out_size, void* d_ws, size_t ws_size,
                              hipStream_t stream) {
    const float* x       = (const float*)d_in[0];
    float*       out     = (float*)d_out;
    float*       partial = (float*)d_ws;   // CHUNKS*NITEMS floats = 225792 B

    dim3 grid(BATCH, CHUNKS);
    gram_kernel<<<grid, TPB, 0, stream>>>(x, partial);
    finalize_kernel<<<1, 256, 0, stream>>>(partial, out);
}

// Round 14
// 40.362 us; speedup vs baseline: 4.9688x; 1.0817x over previous
//
#include <hip/hip_runtime.h>

#define NMAPS 8
#define BATCH 32
#define DLEN  150528              // 3*224*224
#define D4    (DLEN / 4)          // 37632 float4 per (map, batch) row
#define NPAIR 36                  // i<=j pairs incl diagonal (diag = norm^2)
#define CHUNKS 32                 // blocks per batch element
#define TPB   256
#define JSTRIDE (CHUNKS * TPB)    // 8192 float4

typedef float floatx4 __attribute__((ext_vector_type(4)));

// Best-measured variant (R7, 40.05 us): 36 unique pairwise dots per batch
// element, single pass over the 154 MB input, non-temporal float4 direct
// loads, interleaved j-stride, 1024 blocks (4/CU, 16 waves/CU).
// Occupancy>16/CU, LDS staging, fusion all measurably regress (R4-R13).
__global__ __launch_bounds__(TPB) void gram_kernel(const float* __restrict__ xf,
                                                   float* __restrict__ partial) {
    const int b     = blockIdx.x;   // 0..31
    const int chunk = blockIdx.y;   // 0..31
    const int tid   = threadIdx.x;

    const floatx4* xb = reinterpret_cast<const floatx4*>(xf) + (size_t)b * D4;
    const size_t strideI = (size_t)BATCH * D4;   // float4 stride between maps

    float acc[NPAIR];
#pragma unroll
    for (int k = 0; k < NPAIR; ++k) acc[k] = 0.0f;

#pragma unroll 1
    for (int j = chunk * TPB + tid; j < D4; j += JSTRIDE) {
        floatx4 v[NMAPS];
#pragma unroll
        for (int i = 0; i < NMAPS; ++i)
            v[i] = __builtin_nontemporal_load(&xb[(size_t)i * strideI + j]);
        int k = 0;
#pragma unroll
        for (int i = 0; i < NMAPS; ++i) {
#pragma unroll
            for (int jj = i; jj < NMAPS; ++jj) {
                acc[k] += v[i].x * v[jj].x + v[i].y * v[jj].y +
                          v[i].z * v[jj].z + v[i].w * v[jj].w;
                ++k;
            }
        }
    }

    // wave shuffle reduce, then cross-wave LDS reduce
    const int lane = tid & 63;
    const int wave = tid >> 6;
    __shared__ float red[TPB / 64][NPAIR];
#pragma unroll
    for (int k = 0; k < NPAIR; ++k) {
        float s = acc[k];
#pragma unroll
        for (int off = 32; off > 0; off >>= 1) s += __shfl_down(s, off, 64);
        if (lane == 0) red[wave][k] = s;
    }
    __syncthreads();
    if (tid < NPAIR) {
        // layout: partial[(b*36+k)*CHUNKS + chunk] -> finalize reads float4
        partial[((size_t)b * NPAIR + tid) * CHUNKS + chunk] =
            red[0][tid] + red[1][tid] + red[2][tid] + red[3][tid];
    }
}

// Kernel 2: sum partials over chunks, then cosine epilogue. One block.
__global__ __launch_bounds__(256) void finalize_kernel(const float* __restrict__ partial,
                                                       float* __restrict__ out) {
    const int tid = threadIdx.x;
    __shared__ float dots_s[BATCH * NPAIR];   // [b][k]
    __shared__ float norms[BATCH][NMAPS];

    for (int item = tid; item < BATCH * NPAIR; item += 256) {
        const float4* p = reinterpret_cast<const float4*>(partial + (size_t)item * CHUNKS);
        float s = 0.0f;
#pragma unroll
        for (int c = 0; c < CHUNKS / 4; ++c) {
            float4 t = p[c];
            s += t.x + t.y + t.z + t.w;
        }
        dots_s[item] = s;
    }
    __syncthreads();
    {
        int bb = tid >> 3, i = tid & 7;             // 256 = 32*8
        int diag = 8 * i - (i * (i - 1)) / 2;
        norms[bb][i] = sqrtf(dots_s[bb * NPAIR + diag]);
    }
    __syncthreads();

    float sum = 0.0f;
    for (int item = tid; item < 28 * BATCH; item += 256) {
        int p = item >> 5;   // pair 0..27
        int bb = item & 31;
        int i = 0, rem = p;
        while (rem >= 7 - i) { rem -= 7 - i; ++i; }
        int j = i + 1 + rem;
        int k = 8 * i - (i * (i - 1)) / 2 + (j - i);
        float d   = fabsf(dots_s[bb * NPAIR + k]);
        float den = fmaxf(norms[bb][i] * norms[bb][j], 1e-8f);
        sum += d / den;
    }

    const int lane = tid & 63, wave = tid >> 6;
    __shared__ float red2[4];
#pragma unroll
    for (int off = 32; off > 0; off >>= 1) sum += __shfl_down(sum, off, 64);
    if (lane == 0) red2[wave] = sum;
    __syncthreads();
    if (tid == 0)
        out[0] = (red2[0] + red2[1] + red2[2] + red2[3]) / (28.0f * BATCH);
}

extern "C" void kernel_launch(void* const* d_in, const int* in_sizes, int n_in,
                              void* d_out, int out_size, void* d_ws, size_t ws_size,
                              hipStream_t stream) {
    const float* x       = (const float*)d_in[0];
    float*       out     = (float*)d_out;
    float*       partial = (float*)d_ws;   // BATCH*NPAIR*CHUNKS floats = 147 KB

    dim3 grid(BATCH, CHUNKS);
    gram_kernel<<<grid, TPB, 0, stream>>>(x, partial);
    finalize_kernel<<<1, 256, 0, stream>>>(partial, out);
}